// Round 1
// baseline (299.025 us; speedup 1.0000x reference)
//
#include <hip/hip_runtime.h>
#include <math.h>

constexpr int LL = 16384;
constexpr int HH = 8;
constexpr int DD = 16;
constexpr float EPS = 1e-6f;
constexpr float LN_EPS = 1e-5f;

// workspace layout (float offsets)
constexpr int OFF_QSUM = 0;      // [32][16]
constexpr int OFF_KSUM = 512;    // [32][16]
constexpr int OFF_QN   = 1024;   // [32][16]
constexpr int OFF_KN   = 1536;   // [32][16]
constexpr int OFF_SMAX = 2048;   // [32]
constexpr int OFF_SSUM = 2080;   // [32]
constexpr int OFF_KV   = 2112;   // [32][256]
constexpr int OFF_NCR  = 10304;  // [32][16384]

__device__ __forceinline__ float sigmoidf_(float x) { return 1.0f / (1.0f + __expf(-x)); }

__device__ __forceinline__ float waveSum(float v) {
#pragma unroll
  for (int off = 32; off; off >>= 1) v += __shfl_down(v, off, 64);
  return v;
}
__device__ __forceinline__ float waveMax(float v) {
#pragma unroll
  for (int off = 32; off; off >>= 1) v = fmaxf(v, __shfl_down(v, off, 64));
  return v;
}

__device__ __forceinline__ void load_row_sig(const float* p, float* r) {
  const float4* p4 = reinterpret_cast<const float4*>(p);
#pragma unroll
  for (int j = 0; j < 4; ++j) {
    float4 a = p4[j];
    r[4 * j + 0] = sigmoidf_(a.x);
    r[4 * j + 1] = sigmoidf_(a.y);
    r[4 * j + 2] = sigmoidf_(a.z);
    r[4 * j + 3] = sigmoidf_(a.w);
  }
}
__device__ __forceinline__ void load_row_raw(const float* p, float* r) {
  const float4* p4 = reinterpret_cast<const float4*>(p);
#pragma unroll
  for (int j = 0; j < 4; ++j) {
    float4 a = p4[j];
    r[4 * j + 0] = a.x;
    r[4 * j + 1] = a.y;
    r[4 * j + 2] = a.z;
    r[4 * j + 3] = a.w;
  }
}

// P1: q_sum, k_sum per (n,h,d)
__global__ __launch_bounds__(256) void k_sums(const float* __restrict__ Q,
                                              const float* __restrict__ K,
                                              float* __restrict__ ws) {
  const int nh = blockIdx.x, n = nh >> 3, h = nh & 7;
  const int tid = threadIdx.x;
  float acc[32];
#pragma unroll
  for (int i = 0; i < 32; ++i) acc[i] = 0.f;
  const int l0 = blockIdx.y * 512;
  for (int it = 0; it < 2; ++it) {
    const int l = l0 + it * 256 + tid;
    const int base = (n * LL + l) * (HH * DD) + h * DD;
    float qv[16], kv[16];
    load_row_sig(Q + base, qv);
    load_row_sig(K + base, kv);
#pragma unroll
    for (int d = 0; d < 16; ++d) {
      acc[d] += qv[d];
      acc[16 + d] += kv[d];
    }
  }
  __shared__ float red[4][32];
  const int wave = tid >> 6, lane = tid & 63;
#pragma unroll
  for (int i = 0; i < 32; ++i) {
    float s = waveSum(acc[i]);
    if (lane == 0) red[wave][i] = s;
  }
  __syncthreads();
  if (tid < 32) {
    float s = red[0][tid] + red[1][tid] + red[2][tid] + red[3][tid];
    float* dst = (tid < 16) ? (ws + OFF_QSUM + nh * 16 + tid)
                            : (ws + OFF_KSUM + nh * 16 + (tid - 16));
    atomicAdd(dst, s);
  }
}

// P2: qn_sum = sum_l q*nr, kn_sum = sum_s k*nc
__global__ __launch_bounds__(256) void k_refine_sums(const float* __restrict__ Q,
                                                     const float* __restrict__ K,
                                                     float* __restrict__ ws) {
  const int nh = blockIdx.x, n = nh >> 3, h = nh & 7;
  const int tid = threadIdx.x;
  float qsE[16], ksE[16];
#pragma unroll
  for (int i = 0; i < 16; ++i) {
    qsE[i] = ws[OFF_QSUM + nh * 16 + i] + EPS;
    ksE[i] = ws[OFF_KSUM + nh * 16 + i] + EPS;
  }
  float acc[32];
#pragma unroll
  for (int i = 0; i < 32; ++i) acc[i] = 0.f;
  const int l0 = blockIdx.y * 512;
  for (int it = 0; it < 2; ++it) {
    const int l = l0 + it * 256 + tid;
    const int base = (n * LL + l) * (HH * DD) + h * DD;
    float qv[16], kv[16];
    load_row_sig(Q + base, qv);
    load_row_sig(K + base, kv);
    float dr = 0.f, dc = 0.f;
#pragma unroll
    for (int d = 0; d < 16; ++d) {
      dr += (qv[d] + EPS) * ksE[d];
      dc += (kv[d] + EPS) * qsE[d];
    }
    const float nr = 1.f / dr, nc = 1.f / dc;
#pragma unroll
    for (int d = 0; d < 16; ++d) {
      acc[d] += qv[d] * nr;
      acc[16 + d] += kv[d] * nc;
    }
  }
  __shared__ float red[4][32];
  const int wave = tid >> 6, lane = tid & 63;
#pragma unroll
  for (int i = 0; i < 32; ++i) {
    float s = waveSum(acc[i]);
    if (lane == 0) red[wave][i] = s;
  }
  __syncthreads();
  if (tid < 32) {
    float s = red[0][tid] + red[1][tid] + red[2][tid] + red[3][tid];
    float* dst = (tid < 16) ? (ws + OFF_QN + nh * 16 + tid)
                            : (ws + OFF_KN + nh * 16 + (tid - 16));
    atomicAdd(dst, s);
  }
}

// P3: ncr_raw[s] = dot(k[s]+EPS, qn_sum+EPS)
__global__ __launch_bounds__(256) void k_ncr(const float* __restrict__ K,
                                             float* __restrict__ ws) {
  const int nh = blockIdx.x, n = nh >> 3, h = nh & 7;
  const int tid = threadIdx.x;
  float qnE[16];
#pragma unroll
  for (int i = 0; i < 16; ++i) qnE[i] = ws[OFF_QN + nh * 16 + i] + EPS;
  const int l = blockIdx.y * 256 + tid;
  const int base = (n * LL + l) * (HH * DD) + h * DD;
  float kv[16];
  load_row_sig(K + base, kv);
  float s = 0.f;
#pragma unroll
  for (int d = 0; d < 16; ++d) s += (kv[d] + EPS) * qnE[d];
  ws[OFF_NCR + nh * LL + l] = s;
}

// P3b: softmax stats (max, sumexp) per nh
__global__ __launch_bounds__(256) void k_smstats(float* __restrict__ ws) {
  const int nh = blockIdx.x, tid = threadIdx.x;
  const int wave = tid >> 6, lane = tid & 63;
  const float* ncr = ws + OFF_NCR + nh * LL;
  __shared__ float red[8];
  float m = -1e30f;
  for (int i = tid; i < LL; i += 256) m = fmaxf(m, ncr[i]);
  m = waveMax(m);
  if (lane == 0) red[wave] = m;
  __syncthreads();
  m = fmaxf(fmaxf(red[0], red[1]), fmaxf(red[2], red[3]));
  float s = 0.f;
  for (int i = tid; i < LL; i += 256) s += __expf(ncr[i] - m);
  s = waveSum(s);
  if (lane == 0) red[4 + wave] = s;
  __syncthreads();
  if (tid == 0) {
    ws[OFF_SMAX + nh] = m;
    ws[OFF_SSUM + nh] = red[4] + red[5] + red[6] + red[7];
  }
}

// P4: kv[d][e] = sum_s k[s,d] * v[s,e] * w[s]
__global__ __launch_bounds__(256) void k_kv(const float* __restrict__ K,
                                            const float* __restrict__ V,
                                            float* __restrict__ ws) {
  const int nh = blockIdx.x, n = nh >> 3, h = nh & 7;
  const int tid = threadIdx.x;
  __shared__ float kwT[16 * 260];
  __shared__ float vT[16 * 260];
  __shared__ float kvred[256];
  const float m = ws[OFF_SMAX + nh];
  const float wscale = (float)LL / ws[OFF_SSUM + nh];
  const int seg = tid >> 6, p = tid & 63, db = p >> 3, eb = p & 7;
  const int d0 = db * 2, e0 = eb * 2;
  float a00 = 0.f, a01 = 0.f, a10 = 0.f, a11 = 0.f;
  for (int t = 0; t < 2; ++t) {
    const int l = (blockIdx.y * 2 + t) * 256 + tid;
    const int base = (n * LL + l) * (HH * DD) + h * DD;
    float kv[16], vv[16];
    load_row_sig(K + base, kv);
    load_row_raw(V + base, vv);
    const float w = __expf(ws[OFF_NCR + nh * LL + l] - m) * wscale;
#pragma unroll
    for (int d = 0; d < 16; ++d) {
      kwT[d * 260 + tid] = kv[d] * w;
      vT[d * 260 + tid] = vv[d];
    }
    __syncthreads();
#pragma unroll
    for (int j = 0; j < 16; ++j) {
      const int r = seg * 64 + j * 4;
      const float4 x0 = *reinterpret_cast<const float4*>(&kwT[d0 * 260 + r]);
      const float4 x1 = *reinterpret_cast<const float4*>(&kwT[(d0 + 1) * 260 + r]);
      const float4 y0 = *reinterpret_cast<const float4*>(&vT[e0 * 260 + r]);
      const float4 y1 = *reinterpret_cast<const float4*>(&vT[(e0 + 1) * 260 + r]);
      a00 += x0.x * y0.x + x0.y * y0.y + x0.z * y0.z + x0.w * y0.w;
      a01 += x0.x * y1.x + x0.y * y1.y + x0.z * y1.z + x0.w * y1.w;
      a10 += x1.x * y0.x + x1.y * y0.y + x1.z * y0.z + x1.w * y0.w;
      a11 += x1.x * y1.x + x1.y * y1.y + x1.z * y1.z + x1.w * y1.w;
    }
    __syncthreads();
  }
  kvred[tid] = 0.f;
  __syncthreads();
  atomicAdd(&kvred[d0 * 16 + e0], a00);
  atomicAdd(&kvred[d0 * 16 + e0 + 1], a01);
  atomicAdd(&kvred[(d0 + 1) * 16 + e0], a10);
  atomicAdd(&kvred[(d0 + 1) * 16 + e0 + 1], a11);
  __syncthreads();
  atomicAdd(&ws[OFF_KV + nh * 256 + tid], kvred[tid]);
}

// P5: x = q@kv * nr * nrr + v, LayerNorm, write out
__global__ __launch_bounds__(256) void k_out(const float* __restrict__ Q,
                                             const float* __restrict__ V,
                                             const float* __restrict__ gamma,
                                             const float* __restrict__ beta,
                                             const float* __restrict__ ws,
                                             float* __restrict__ out) {
  const int nh = blockIdx.x, n = nh >> 3, h = nh & 7;
  const int tid = threadIdx.x;
  __shared__ float kvs[256];
  __shared__ float gmb[32];
  kvs[tid] = ws[OFF_KV + nh * 256 + tid];
  if (tid < 16) gmb[tid] = gamma[tid];
  else if (tid < 32) gmb[tid] = beta[tid - 16];
  float ksE[16], knE[16];
#pragma unroll
  for (int i = 0; i < 16; ++i) {
    ksE[i] = ws[OFF_KSUM + nh * 16 + i] + EPS;
    knE[i] = ws[OFF_KN + nh * 16 + i] + EPS;
  }
  __syncthreads();
  const int l = blockIdx.y * 256 + tid;
  const int base = (n * LL + l) * (HH * DD) + h * DD;
  float qv[16], vv[16];
  load_row_sig(Q + base, qv);
  load_row_raw(V + base, vv);
  float dr = 0.f, drr = 0.f;
#pragma unroll
  for (int d = 0; d < 16; ++d) {
    const float qe = qv[d] + EPS;
    dr += qe * ksE[d];
    drr += qe * knE[d];
  }
  const float sc = (1.f / dr) * sigmoidf_(drr);
  float x[16];
#pragma unroll
  for (int e = 0; e < 16; ++e) x[e] = 0.f;
#pragma unroll
  for (int d = 0; d < 16; ++d) {
    const float qd = qv[d];
#pragma unroll
    for (int e = 0; e < 16; ++e) x[e] += qd * kvs[d * 16 + e];
  }
#pragma unroll
  for (int e = 0; e < 16; ++e) x[e] = x[e] * sc + vv[e];
  float mean = 0.f;
#pragma unroll
  for (int e = 0; e < 16; ++e) mean += x[e];
  mean *= (1.f / 16.f);
  float var = 0.f;
#pragma unroll
  for (int e = 0; e < 16; ++e) {
    const float t = x[e] - mean;
    var += t * t;
  }
  var *= (1.f / 16.f);
  const float inv = rsqrtf(var + LN_EPS);
  float y[16];
#pragma unroll
  for (int e = 0; e < 16; ++e) y[e] = (x[e] - mean) * inv * gmb[e] + gmb[16 + e];
  float4* op = reinterpret_cast<float4*>(out + base);
  op[0] = make_float4(y[0], y[1], y[2], y[3]);
  op[1] = make_float4(y[4], y[5], y[6], y[7]);
  op[2] = make_float4(y[8], y[9], y[10], y[11]);
  op[3] = make_float4(y[12], y[13], y[14], y[15]);
}

extern "C" void kernel_launch(void* const* d_in, const int* in_sizes, int n_in,
                              void* d_out, int out_size, void* d_ws, size_t ws_size,
                              hipStream_t stream) {
  const float* Q = (const float*)d_in[0];
  const float* K = (const float*)d_in[1];
  const float* V = (const float*)d_in[2];
  const float* gamma = (const float*)d_in[3];
  const float* beta = (const float*)d_in[4];
  float* ws = (float*)d_ws;
  float* out = (float*)d_out;

  // zero the atomic-accumulator region (ws is poisoned 0xAA before each call)
  hipMemsetAsync(d_ws, 0, (size_t)OFF_NCR * sizeof(float), stream);

  const dim3 blk(256);
  k_sums<<<dim3(32, 32), blk, 0, stream>>>(Q, K, ws);
  k_refine_sums<<<dim3(32, 32), blk, 0, stream>>>(Q, K, ws);
  k_ncr<<<dim3(32, 64), blk, 0, stream>>>(K, ws);
  k_smstats<<<dim3(32), blk, 0, stream>>>(ws);
  k_kv<<<dim3(32, 32), blk, 0, stream>>>(K, V, ws);
  k_out<<<dim3(32, 64), blk, 0, stream>>>(Q, V, gamma, beta, ws, out);
}